// Round 1
// baseline (349.165 us; speedup 1.0000x reference)
//
#include <hip/hip_runtime.h>
#include <math.h>

#define BATCH 16
#define IMG 96
#define NWIN 9
#define M_FILT 16
#define S 88
#define SP 22
#define FIN (M_FILT * SP * SP)   // 7744

// ---------------------------------------------------------------------------
// Kernel 1: dendrite (atan-gated window product/log-sum) + 4x4 maxpool, fused.
// One thread per pooled output (b, pi, pj, m); flat layout = b*FIN + (pi*SP+pj)*16 + m
// which matches the reference's [B,SP,SP,M] row-major flatten.
// ---------------------------------------------------------------------------
__global__ __launch_bounds__(256) void dendrite_pool_kernel(
    const float* __restrict__ x,      // [B,96,96]
    const float* __restrict__ w,      // [16,9,9]
    const float* __restrict__ q,      // [16,9,9]
    float* __restrict__ pooled)       // [B, FIN]
{
    __shared__ float sw[M_FILT * 81];
    __shared__ float sq[M_FILT * 81];
    for (int i = threadIdx.x; i < M_FILT * 81; i += 256) {
        sw[i] = w[i];
        sq[i] = q[i];
    }
    __syncthreads();

    int tid = blockIdx.x * 256 + threadIdx.x;
    if (tid >= BATCH * FIN) return;

    int b   = tid / FIN;
    int rem = tid - b * FIN;
    int m   = rem & 15;          // filter index
    int pp  = rem >> 4;          // pooled spatial index pi*SP + pj
    int pj  = pp % SP;
    int pi  = pp / SP;

    const float* xb = x + b * IMG * IMG;
    const float* wm = sw + m * 81;
    const float* qm = sq + m * 81;

    const float inv_pi = 0.31830988618379067f;

    float best = -1e30f;
    #pragma unroll
    for (int di = 0; di < 4; ++di) {
        int i0 = pi * 4 + di;
        #pragma unroll
        for (int dj = 0; dj < 4; ++dj) {
            int j0 = pj * 4 + dj;
            float acc = 0.0f;
            #pragma unroll
            for (int r = 0; r < NWIN; ++r) {
                const float* xr = xb + (i0 + r) * IMG + j0;
                float prod = 1.0f;
                #pragma unroll
                for (int c = 0; c < NWIN; ++c) {
                    float z = 10.0f * (xr[c] * wm[r * 9 + c] - qm[r * 9 + c]);
                    float t = 1.1f + atanf(z) * inv_pi;   // (pi+2*atan)/(2pi) + 0.6
                    prod *= t;
                }
                acc += __logf(prod);
            }
            best = fmaxf(best, acc);
        }
    }
    pooled[tid] = best;
}

// ---------------------------------------------------------------------------
// Kernel 2: FC1 (7744 -> 128) + bias + ReLU. One wave per (b, o).
// FIN = 7744 = 64 * 121 exactly.
// ---------------------------------------------------------------------------
__global__ __launch_bounds__(256) void fc1_kernel(
    const float* __restrict__ pooled,  // [B, FIN]
    const float* __restrict__ w1,      // [128, FIN]
    const float* __restrict__ b1,      // [128]
    float* __restrict__ h)             // [B, 128]
{
    int gwave = (blockIdx.x * 256 + threadIdx.x) >> 6;
    int lane  = threadIdx.x & 63;
    if (gwave >= BATCH * 128) return;
    int b = gwave >> 7;
    int o = gwave & 127;

    const float* y  = pooled + b * FIN;
    const float* wr = w1 + o * FIN;

    float s = 0.0f;
    #pragma unroll 4
    for (int f = lane; f < FIN; f += 64) {
        s += y[f] * wr[f];
    }
    // wave64 butterfly reduce
    #pragma unroll
    for (int off = 32; off > 0; off >>= 1) {
        s += __shfl_down(s, off, 64);
    }
    if (lane == 0) {
        h[b * 128 + o] = fmaxf(s + b1[o], 0.0f);
    }
}

// ---------------------------------------------------------------------------
// Kernel 3: FC2 (128 -> 10) + bias. One thread per output, single block.
// ---------------------------------------------------------------------------
__global__ __launch_bounds__(192) void fc2_kernel(
    const float* __restrict__ h,       // [B, 128]
    const float* __restrict__ w2,      // [10, 128]
    const float* __restrict__ b2,      // [10]
    float* __restrict__ out)           // [B, 10]
{
    int t = threadIdx.x;
    if (t >= BATCH * 10) return;
    int b = t / 10;
    int c = t - b * 10;
    const float* hb = h + b * 128;
    const float* wr = w2 + c * 128;
    float s = 0.0f;
    #pragma unroll 8
    for (int k = 0; k < 128; ++k) {
        s += hb[k] * wr[k];
    }
    out[t] = s + b2[c];
}

// ---------------------------------------------------------------------------
extern "C" void kernel_launch(void* const* d_in, const int* in_sizes, int n_in,
                              void* d_out, int out_size, void* d_ws, size_t ws_size,
                              hipStream_t stream)
{
    const float* x    = (const float*)d_in[0];
    const float* w    = (const float*)d_in[1];
    const float* q    = (const float*)d_in[2];
    const float* fc1w = (const float*)d_in[3];
    const float* fc1b = (const float*)d_in[4];
    const float* fc2w = (const float*)d_in[5];
    const float* fc2b = (const float*)d_in[6];
    float* out = (float*)d_out;

    float* pooled = (float*)d_ws;                 // B*FIN floats = 495,616 B
    float* h      = pooled + BATCH * FIN;         // B*128 floats = 8,192 B

    // Kernel 1: 123,904 threads
    int n1 = BATCH * FIN;
    dendrite_pool_kernel<<<(n1 + 255) / 256, 256, 0, stream>>>(x, w, q, pooled);

    // Kernel 2: one wave per (b,o) -> 2048 waves -> 512 blocks of 256
    int nwaves = BATCH * 128;
    fc1_kernel<<<(nwaves * 64 + 255) / 256, 256, 0, stream>>>(pooled, fc1w, fc1b, h);

    // Kernel 3: single block
    fc2_kernel<<<1, 192, 0, stream>>>(h, fc2w, fc2b, out);
}

// Round 2
// 150.705 us; speedup vs baseline: 2.3169x; 2.3169x over previous
//
#include <hip/hip_runtime.h>

#define BATCH 16
#define IMG 96
#define NWIN 9
#define M_FILT 16
#define S 88
#define SP 22
#define FIN (M_FILT * SP * SP)   // 7744
#define NPP (SP * SP)            // 484

// t(z) = 1.1 + atan(z)/pi, fast approx.
// |z|<=1: odd minimax poly P(z) ~ atan(z)/pi (1/pi folded into coeffs).
// |z|>1 : atan(z) = copysign(pi/2, z) - atan(1/z), 1/z via v_rcp_f32.
__device__ __forceinline__ float dend_t(float z) {
    const float K0 =  0.3183026482f;   //  0.99997726 / pi
    const float K1 = -0.10587727f;     // -0.33262347 / pi
    const float K2 =  0.06160671f;     //  0.19354346 / pi
    const float K3 = -0.03706178f;     // -0.11643287 / pi
    const float K4 =  0.01676006f;     //  0.05265332 / pi
    float inv = __builtin_amdgcn_rcpf(z);
    bool  big = __builtin_fabsf(z) > 1.0f;
    float u = big ? inv : z;
    float s = u * u;
    float p = fmaf(s, K4, K3);
    p = fmaf(s, p, K2);
    p = fmaf(s, p, K1);
    p = fmaf(s, p, K0);
    p = p * u;                                   // ~ atan(u)/pi
    float bb = 1.1f + __builtin_copysignf(0.5f, z);
    return big ? bb - p : 1.1f + p;
}

// ---------------------------------------------------------------------------
// Kernel 1: dendrite + 4x4 maxpool.
// Thread layout: tid = [ b , pp(=pi*22+pj) , di(2b) , m(4b) ]  (m fastest).
// Each thread: one pool-row di, all 4 dj windows, all 9x9 elements.
// Max over di via shfl_xor(16),(32); lanes with di==0 write.
// ---------------------------------------------------------------------------
__global__ __launch_bounds__(256, 4) void dendrite_pool_kernel(
    const float* __restrict__ x,      // [B,96,96]
    const float* __restrict__ w,      // [16,9,9]
    const float* __restrict__ q,      // [16,9,9]
    float* __restrict__ pooled)       // [B, FIN]
{
    __shared__ float sw[M_FILT * 81];    // 10*w
    __shared__ float snq[M_FILT * 81];   // -10*q
    for (int i = threadIdx.x; i < M_FILT * 81; i += 256) {
        sw[i]  = 10.0f * w[i];
        snq[i] = -10.0f * q[i];
    }
    __syncthreads();

    int t    = blockIdx.x * 256 + threadIdx.x;
    int m    = t & 15;
    int di   = (t >> 4) & 3;
    int rest = t >> 6;                // [0, B*484)
    int b    = rest / NPP;
    int pp   = rest - b * NPP;
    int pj   = pp % SP;
    int pi   = pp / SP;

    const float* xb = x + b * IMG * IMG + (pi * 4 + di) * IMG + pj * 4;
    const float* wm = sw  + m * 81;
    const float* qm = snq + m * 81;

    float acc0 = 0.f, acc1 = 0.f, acc2 = 0.f, acc3 = 0.f;   // per dj, in log2

    #pragma unroll 1
    for (int r = 0; r < NWIN; ++r) {
        const float4* xr = reinterpret_cast<const float4*>(xb + r * IMG);
        float4 a = xr[0], c4 = xr[1], e4 = xr[2];
        float xv[12] = {a.x,a.y,a.z,a.w, c4.x,c4.y,c4.z,c4.w, e4.x,e4.y,e4.z,e4.w};
        float wr_[9], qr_[9];
        #pragma unroll
        for (int c = 0; c < 9; ++c) { wr_[c] = wm[r*9+c]; qr_[c] = qm[r*9+c]; }
        float p0 = 1.f, p1 = 1.f, p2 = 1.f, p3 = 1.f;
        #pragma unroll
        for (int c = 0; c < 9; ++c) {
            p0 *= dend_t(fmaf(xv[c + 0], wr_[c], qr_[c]));
            p1 *= dend_t(fmaf(xv[c + 1], wr_[c], qr_[c]));
            p2 *= dend_t(fmaf(xv[c + 2], wr_[c], qr_[c]));
            p3 *= dend_t(fmaf(xv[c + 3], wr_[c], qr_[c]));
        }
        acc0 += __builtin_amdgcn_logf(p0);   // log2; scale to ln at the end
        acc1 += __builtin_amdgcn_logf(p1);
        acc2 += __builtin_amdgcn_logf(p2);
        acc3 += __builtin_amdgcn_logf(p3);
    }

    float best = fmaxf(fmaxf(acc0, acc1), fmaxf(acc2, acc3));
    best = fmaxf(best, __shfl_xor(best, 16, 64));
    best = fmaxf(best, __shfl_xor(best, 32, 64));
    if (di == 0) {
        pooled[b * FIN + pp * 16 + m] = best * 0.69314718056f;
    }
}

// ---------------------------------------------------------------------------
// Kernel 2: FC1 (7744 -> 128) + bias + ReLU. One block per output o.
// Weight row read ONCE; all 16 batch dots accumulate in registers.
// ---------------------------------------------------------------------------
__global__ __launch_bounds__(256) void fc1_kernel(
    const float* __restrict__ pooled,  // [B, FIN]
    const float* __restrict__ w1,      // [128, FIN]
    const float* __restrict__ b1,      // [128]
    float* __restrict__ h)             // [B, 128]
{
    int o = blockIdx.x;
    const float* wr = w1 + o * FIN;

    float acc[BATCH];
    #pragma unroll
    for (int b = 0; b < BATCH; ++b) acc[b] = 0.f;

    for (int f = threadIdx.x; f < FIN; f += 256) {
        float wv = wr[f];
        #pragma unroll
        for (int b = 0; b < BATCH; ++b)
            acc[b] = fmaf(pooled[b * FIN + f], wv, acc[b]);
    }

    #pragma unroll
    for (int b = 0; b < BATCH; ++b) {
        #pragma unroll
        for (int off = 32; off > 0; off >>= 1)
            acc[b] += __shfl_down(acc[b], off, 64);
    }

    __shared__ float red[4][BATCH];
    int wid = threadIdx.x >> 6, lane = threadIdx.x & 63;
    if (lane == 0) {
        #pragma unroll
        for (int b = 0; b < BATCH; ++b) red[wid][b] = acc[b];
    }
    __syncthreads();
    if (threadIdx.x < BATCH) {
        int b = threadIdx.x;
        float s_ = red[0][b] + red[1][b] + red[2][b] + red[3][b] + b1[o];
        h[b * 128 + o] = fmaxf(s_, 0.f);
    }
}

// ---------------------------------------------------------------------------
// Kernel 3: FC2 (128 -> 10) + bias.
// ---------------------------------------------------------------------------
__global__ __launch_bounds__(192) void fc2_kernel(
    const float* __restrict__ h,       // [B, 128]
    const float* __restrict__ w2,      // [10, 128]
    const float* __restrict__ b2,      // [10]
    float* __restrict__ out)           // [B, 10]
{
    int t = threadIdx.x;
    if (t >= BATCH * 10) return;
    int b = t / 10;
    int c = t - b * 10;
    const float* hb = h + b * 128;
    const float* wr = w2 + c * 128;
    float s = 0.0f;
    #pragma unroll 8
    for (int k = 0; k < 128; ++k) s += hb[k] * wr[k];
    out[t] = s + b2[c];
}

// ---------------------------------------------------------------------------
extern "C" void kernel_launch(void* const* d_in, const int* in_sizes, int n_in,
                              void* d_out, int out_size, void* d_ws, size_t ws_size,
                              hipStream_t stream)
{
    const float* x    = (const float*)d_in[0];
    const float* w    = (const float*)d_in[1];
    const float* q    = (const float*)d_in[2];
    const float* fc1w = (const float*)d_in[3];
    const float* fc1b = (const float*)d_in[4];
    const float* fc2w = (const float*)d_in[5];
    const float* fc2b = (const float*)d_in[6];
    float* out = (float*)d_out;

    float* pooled = (float*)d_ws;                 // B*FIN floats
    float* h      = pooled + BATCH * FIN;         // B*128 floats

    // Kernel 1: B * 484 * 4(di) * 16(m) = 495,616 threads = 1936 blocks
    dendrite_pool_kernel<<<1936, 256, 0, stream>>>(x, w, q, pooled);

    // Kernel 2: one block per output neuron
    fc1_kernel<<<128, 256, 0, stream>>>(pooled, fc1w, fc1b, h);

    // Kernel 3: single block
    fc2_kernel<<<1, 192, 0, stream>>>(h, fc2w, fc2b, out);
}

// Round 3
// 145.591 us; speedup vs baseline: 2.3983x; 1.0351x over previous
//
#include <hip/hip_runtime.h>

#define BATCH 16
#define IMG 96
#define NWIN 9
#define M_FILT 16
#define SP 22
#define FIN (M_FILT * SP * SP)   // 7744
#define NPP (SP * SP)            // 484

// t(z) = 1.1 + atan(z)/pi.
// |z|<=1: t = fma(z, P(z^2), 1.1)          P odd-poly coeffs = minimax(atan)/pi
// |z|>1 : atan(z)/pi = sign(z)*0.5 - atan(1/z)/pi = sign(z)*0.5 + P(-1/z)
//         t = fma(u, P(u^2), 1.1 + copysign(0.5,z)),  u = -1/z
__device__ __forceinline__ float dend_t(float z) {
    const float K0 =  0.3183026482f;   //  0.99997726 / pi
    const float K1 = -0.10587727f;     // -0.33262347 / pi
    const float K2 =  0.06160671f;     //  0.19354346 / pi
    const float K3 = -0.03706178f;     // -0.11643287 / pi
    const float K4 =  0.01676006f;     //  0.05265332 / pi
    float r   = __builtin_amdgcn_rcpf(z);
    bool  big = __builtin_fabsf(z) > 1.0f;
    float u   = big ? -r : z;                 // cndmask w/ neg modifier
    float s   = u * u;
    float p   = fmaf(s, K4, K3);
    p = fmaf(s, p, K2);
    p = fmaf(s, p, K1);
    p = fmaf(s, p, K0);
    float sg  = __builtin_copysignf(0.5f, z); // v_bfi
    float c   = 1.1f + (big ? sg : 0.0f);     // cndmask + add
    return fmaf(u, p, c);
}

// ---------------------------------------------------------------------------
// Kernel 1: dendrite + 4x4 maxpool.
// tid = [ b , pp , di(2b) , m(4b) ].  Each thread: 4 dj-windows of one pool
// row di, running PRODUCT per window over all 81 elems (no per-row log:
// sum_r log(prod_c) == log(prod_81), and max commutes with log).
// max over di via shfl_xor(16),(32); single log2 at the end.
// ---------------------------------------------------------------------------
__global__ __launch_bounds__(256, 4) void dendrite_pool_kernel(
    const float* __restrict__ x,      // [B,96,96]
    const float* __restrict__ w,      // [16,9,9]
    const float* __restrict__ q,      // [16,9,9]
    float* __restrict__ pooled)       // [B, FIN]
{
    // rows padded to 12 floats -> 48B row stride (16B aligned) for b128 reads
    __shared__ float sw[M_FILT][NWIN][12];    // 10*w
    __shared__ float sq[M_FILT][NWIN][12];    // -10*q
    for (int i = threadIdx.x; i < M_FILT * NWIN * 12; i += 256) {
        int c  = i % 12;
        int mr = i / 12;
        float vw = 0.f, vq = 0.f;
        if (c < 9) {
            int src = mr * 9 + c;
            vw = 10.0f * w[src];
            vq = -10.0f * q[src];
        }
        ((float*)sw)[i] = vw;
        ((float*)sq)[i] = vq;
    }
    __syncthreads();

    int t    = blockIdx.x * 256 + threadIdx.x;
    int m    = t & 15;
    int di   = (t >> 4) & 3;
    int rest = t >> 6;                // [0, B*484)
    int b    = rest / NPP;
    int pp   = rest - b * NPP;
    int pj   = pp % SP;
    int pi   = pp / SP;

    const float* xb = x + b * IMG * IMG + (pi * 4 + di) * IMG + pj * 4;

    float pr0 = 1.f, pr1 = 1.f, pr2 = 1.f, pr3 = 1.f;

    #pragma unroll 1
    for (int r = 0; r < NWIN; ++r) {
        const float4* xr = reinterpret_cast<const float4*>(xb + r * IMG);
        float4 A = xr[0], B4 = xr[1], C4 = xr[2];
        float xv[12] = {A.x,A.y,A.z,A.w, B4.x,B4.y,B4.z,B4.w, C4.x,C4.y,C4.z,C4.w};

        const float4* wrow = reinterpret_cast<const float4*>(&sw[m][r][0]);
        const float4* qrow = reinterpret_cast<const float4*>(&sq[m][r][0]);
        float4 W0 = wrow[0], W1 = wrow[1];
        float4 Q0 = qrow[0], Q1 = qrow[1];
        float wv[9] = {W0.x,W0.y,W0.z,W0.w, W1.x,W1.y,W1.z,W1.w, sw[m][r][8]};
        float qv[9] = {Q0.x,Q0.y,Q0.z,Q0.w, Q1.x,Q1.y,Q1.z,Q1.w, sq[m][r][8]};

        #pragma unroll
        for (int c = 0; c < 9; ++c) {
            pr0 *= dend_t(fmaf(xv[c + 0], wv[c], qv[c]));
            pr1 *= dend_t(fmaf(xv[c + 1], wv[c], qv[c]));
            pr2 *= dend_t(fmaf(xv[c + 2], wv[c], qv[c]));
            pr3 *= dend_t(fmaf(xv[c + 3], wv[c], qv[c]));
        }
    }

    float best = fmaxf(fmaxf(pr0, pr1), fmaxf(pr2, pr3));
    best = fmaxf(best, __shfl_xor(best, 16, 64));
    best = fmaxf(best, __shfl_xor(best, 32, 64));
    if (di == 0) {
        // ln(best) = log2(best) * ln(2)
        pooled[b * FIN + pp * 16 + m] = __builtin_amdgcn_logf(best) * 0.69314718056f;
    }
}

// ---------------------------------------------------------------------------
// Kernel 2: FC1 (7744 -> 128) + bias + ReLU. One block per output o.
// ---------------------------------------------------------------------------
__global__ __launch_bounds__(256) void fc1_kernel(
    const float* __restrict__ pooled,  // [B, FIN]
    const float* __restrict__ w1,      // [128, FIN]
    const float* __restrict__ b1,      // [128]
    float* __restrict__ h)             // [B, 128]
{
    int o = blockIdx.x;
    const float* wr = w1 + o * FIN;

    float acc[BATCH];
    #pragma unroll
    for (int b = 0; b < BATCH; ++b) acc[b] = 0.f;

    for (int f = threadIdx.x; f < FIN; f += 256) {
        float wv = wr[f];
        #pragma unroll
        for (int b = 0; b < BATCH; ++b)
            acc[b] = fmaf(pooled[b * FIN + f], wv, acc[b]);
    }

    #pragma unroll
    for (int b = 0; b < BATCH; ++b) {
        #pragma unroll
        for (int off = 32; off > 0; off >>= 1)
            acc[b] += __shfl_down(acc[b], off, 64);
    }

    __shared__ float red[4][BATCH];
    int wid = threadIdx.x >> 6, lane = threadIdx.x & 63;
    if (lane == 0) {
        #pragma unroll
        for (int b = 0; b < BATCH; ++b) red[wid][b] = acc[b];
    }
    __syncthreads();
    if (threadIdx.x < BATCH) {
        int b = threadIdx.x;
        float s_ = red[0][b] + red[1][b] + red[2][b] + red[3][b] + b1[o];
        h[b * 128 + o] = fmaxf(s_, 0.f);
    }
}

// ---------------------------------------------------------------------------
// Kernel 3: FC2 (128 -> 10) + bias.
// ---------------------------------------------------------------------------
__global__ __launch_bounds__(192) void fc2_kernel(
    const float* __restrict__ h,       // [B, 128]
    const float* __restrict__ w2,      // [10, 128]
    const float* __restrict__ b2,      // [10]
    float* __restrict__ out)           // [B, 10]
{
    int t = threadIdx.x;
    if (t >= BATCH * 10) return;
    int b = t / 10;
    int c = t - b * 10;
    const float* hb = h + b * 128;
    const float* wr = w2 + c * 128;
    float s = 0.0f;
    #pragma unroll 8
    for (int k = 0; k < 128; ++k) s += hb[k] * wr[k];
    out[t] = s + b2[c];
}

// ---------------------------------------------------------------------------
extern "C" void kernel_launch(void* const* d_in, const int* in_sizes, int n_in,
                              void* d_out, int out_size, void* d_ws, size_t ws_size,
                              hipStream_t stream)
{
    const float* x    = (const float*)d_in[0];
    const float* w    = (const float*)d_in[1];
    const float* q    = (const float*)d_in[2];
    const float* fc1w = (const float*)d_in[3];
    const float* fc1b = (const float*)d_in[4];
    const float* fc2w = (const float*)d_in[5];
    const float* fc2b = (const float*)d_in[6];
    float* out = (float*)d_out;

    float* pooled = (float*)d_ws;                 // B*FIN floats
    float* h      = pooled + BATCH * FIN;         // B*128 floats

    dendrite_pool_kernel<<<1936, 256, 0, stream>>>(x, w, q, pooled);
    fc1_kernel<<<128, 256, 0, stream>>>(pooled, fc1w, fc1b, h);
    fc2_kernel<<<1, 192, 0, stream>>>(h, fc2w, fc2b, out);
}

// Round 5
// 141.286 us; speedup vs baseline: 2.4713x; 1.0305x over previous
//
#include <hip/hip_runtime.h>

#define BATCH 16
#define IMG 96
#define NWIN 9
#define M_FILT 16
#define SP 22
#define FIN (M_FILT * SP * SP)   // 7744
#define NPP (SP * SP)            // 484

typedef float f32x2 __attribute__((ext_vector_type(2)));
typedef float f32x4 __attribute__((ext_vector_type(4)));

__device__ __forceinline__ f32x2 pk_mul(f32x2 a, f32x2 b) {
    f32x2 d;
    asm("v_pk_mul_f32 %0, %1, %2" : "=v"(d) : "v"(a), "v"(b));
    return d;
}
__device__ __forceinline__ f32x2 pk_fma(f32x2 a, f32x2 b, f32x2 c) {
    f32x2 d;
    asm("v_pk_fma_f32 %0, %1, %2, %3" : "=v"(d) : "v"(a), "v"(b), "v"(c));
    return d;
}

// Packed t(z) = 1.1 + atan(z)/pi for both halves of z.
// |z|<=1: t = fma(z, P(z^2), 1.1);  |z|>1: t = fma(-1/z, P(1/z^2), 1.1+copysign(.5,z))
__device__ __forceinline__ f32x2 dend_t2(f32x2 z, f32x2 CK0, f32x2 CK1,
                                         f32x2 CK2, f32x2 CK3, f32x2 CK4) {
    float rx = __builtin_amdgcn_rcpf(z.x);
    float ry = __builtin_amdgcn_rcpf(z.y);
    bool bx = __builtin_fabsf(z.x) > 1.0f;
    bool by = __builtin_fabsf(z.y) > 1.0f;
    f32x2 u;
    u.x = bx ? -rx : z.x;                      // v_cndmask with neg modifier
    u.y = by ? -ry : z.y;
    f32x2 s = pk_mul(u, u);
    f32x2 p = pk_fma(s, CK4, CK3);
    p = pk_fma(s, p, CK2);
    p = pk_fma(s, p, CK1);
    p = pk_fma(s, p, CK0);
    f32x2 c;
    float sgx = __builtin_copysignf(0.5f, z.x);  // v_bfi
    float sgy = __builtin_copysignf(0.5f, z.y);
    c.x = 1.1f + (bx ? sgx : 0.0f);              // cndmask + add
    c.y = 1.1f + (by ? sgy : 0.0f);
    return pk_fma(u, p, c);
}

// ---------------------------------------------------------------------------
// Kernel 1: dendrite + 4x4 maxpool. Block = one (b, m, pp-chunk):
// threads = [ di(2b) | pp_local(6b) ]; m, b block-uniform.
// Per-tap constants {10w, -10q} prescaled into 648B LDS at block start and
// read via uniform-address ds_read_b64 (broadcast, conflict-free, all-VGPR).
// Each thread: 4 dj windows as 2 packed pairs; z generated by 4 scalar v_fma
// (no op_sel broadcast tricks); running product over all 81 taps; single
// log2 after the dj/di max reduction.
// ---------------------------------------------------------------------------
__global__ __launch_bounds__(256) void dendrite_pool_kernel(
    const float* __restrict__ x,      // [B,96,96]
    const float* __restrict__ w,      // [16,9,9]
    const float* __restrict__ q,      // [16,9,9]
    float* __restrict__ pooled)       // [B, FIN]
{
    const int tid   = threadIdx.x;
    const int chunk = blockIdx.x & 7;
    const int m     = (blockIdx.x >> 3) & 15;   // block-uniform
    const int b     = blockIdx.x >> 7;          // block-uniform

    __shared__ f32x2 swq[NWIN * NWIN];          // {10w, -10q} per tap
    if (tid < NWIN * NWIN) {
        float wv = w[m * 81 + tid];
        float qv = q[m * 81 + tid];
        f32x2 t; t.x = 10.0f * wv; t.y = -10.0f * qv;
        swq[tid] = t;
    }
    __syncthreads();

    const int di  = tid & 3;
    const int ppl = tid >> 2;                   // 0..63
    const int pp  = chunk * 64 + ppl;
    const int ppc = pp < NPP ? pp : (NPP - 1);  // clamp to stay in-bounds
    const int pj  = ppc % SP;
    const int pi  = ppc / SP;

    const float* xb = x + b * IMG * IMG + (pi * 4 + di) * IMG + pj * 4;

    const f32x2 CK0 = { 0.3183026482f,  0.3183026482f};
    const f32x2 CK1 = {-0.10587727f,   -0.10587727f};
    const f32x2 CK2 = { 0.06160671f,    0.06160671f};
    const f32x2 CK3 = {-0.03706178f,   -0.03706178f};
    const f32x2 CK4 = { 0.01676006f,    0.01676006f};

    f32x2 PA = {1.0f, 1.0f};   // windows dj=0,1
    f32x2 PB = {1.0f, 1.0f};   // windows dj=2,3

    #pragma unroll 1
    for (int r = 0; r < NWIN; ++r) {
        const f32x4* xr = reinterpret_cast<const f32x4*>(xb + r * IMG);
        f32x4 X0 = xr[0], X1 = xr[1], X2 = xr[2];
        float xv[12] = {X0.x,X0.y,X0.z,X0.w, X1.x,X1.y,X1.z,X1.w, X2.x,X2.y,X2.z,X2.w};

        #pragma unroll
        for (int c = 0; c < 9; ++c) {
            f32x2 wq = swq[r * 9 + c];          // uniform ds_read_b64 broadcast
            f32x2 zA, zB;
            zA.x = fmaf(xv[c + 0], wq.x, wq.y); // z = (10w)*x + (-10q)
            zA.y = fmaf(xv[c + 1], wq.x, wq.y);
            zB.x = fmaf(xv[c + 2], wq.x, wq.y);
            zB.y = fmaf(xv[c + 3], wq.x, wq.y);
            PA = pk_mul(PA, dend_t2(zA, CK0, CK1, CK2, CK3, CK4));
            PB = pk_mul(PB, dend_t2(zB, CK0, CK1, CK2, CK3, CK4));
        }
    }

    float best = fmaxf(fmaxf(PA.x, PA.y), fmaxf(PB.x, PB.y));
    best = fmaxf(best, __shfl_xor(best, 1, 64));   // di reduction
    best = fmaxf(best, __shfl_xor(best, 2, 64));
    if (di == 0 && pp < NPP) {
        pooled[b * FIN + pp * 16 + m] = __builtin_amdgcn_logf(best) * 0.69314718056f;
    }
}

// ---------------------------------------------------------------------------
// Kernel 2: FC1 (7744 -> 128) + bias + ReLU. One block per output o.
// ---------------------------------------------------------------------------
__global__ __launch_bounds__(256) void fc1_kernel(
    const float* __restrict__ pooled,  // [B, FIN]
    const float* __restrict__ w1,      // [128, FIN]
    const float* __restrict__ b1,      // [128]
    float* __restrict__ h)             // [B, 128]
{
    int o = blockIdx.x;
    const float* wr = w1 + o * FIN;

    float acc[BATCH];
    #pragma unroll
    for (int b = 0; b < BATCH; ++b) acc[b] = 0.f;

    for (int f = threadIdx.x; f < FIN; f += 256) {
        float wv = wr[f];
        #pragma unroll
        for (int b = 0; b < BATCH; ++b)
            acc[b] = fmaf(pooled[b * FIN + f], wv, acc[b]);
    }

    #pragma unroll
    for (int b = 0; b < BATCH; ++b) {
        #pragma unroll
        for (int off = 32; off > 0; off >>= 1)
            acc[b] += __shfl_down(acc[b], off, 64);
    }

    __shared__ float red[4][BATCH];
    int wid = threadIdx.x >> 6, lane = threadIdx.x & 63;
    if (lane == 0) {
        #pragma unroll
        for (int b = 0; b < BATCH; ++b) red[wid][b] = acc[b];
    }
    __syncthreads();
    if (threadIdx.x < BATCH) {
        int b = threadIdx.x;
        float s_ = red[0][b] + red[1][b] + red[2][b] + red[3][b] + b1[o];
        h[b * 128 + o] = fmaxf(s_, 0.f);
    }
}

// ---------------------------------------------------------------------------
// Kernel 3: FC2 (128 -> 10) + bias.
// ---------------------------------------------------------------------------
__global__ __launch_bounds__(192) void fc2_kernel(
    const float* __restrict__ h,       // [B, 128]
    const float* __restrict__ w2,      // [10, 128]
    const float* __restrict__ b2,      // [10]
    float* __restrict__ out)           // [B, 10]
{
    int t = threadIdx.x;
    if (t >= BATCH * 10) return;
    int b = t / 10;
    int c = t - b * 10;
    const float* hb = h + b * 128;
    const float* wr = w2 + c * 128;
    float s = 0.0f;
    #pragma unroll 8
    for (int k = 0; k < 128; ++k) s += hb[k] * wr[k];
    out[t] = s + b2[c];
}

// ---------------------------------------------------------------------------
extern "C" void kernel_launch(void* const* d_in, const int* in_sizes, int n_in,
                              void* d_out, int out_size, void* d_ws, size_t ws_size,
                              hipStream_t stream)
{
    const float* x    = (const float*)d_in[0];
    const float* w    = (const float*)d_in[1];
    const float* q    = (const float*)d_in[2];
    const float* fc1w = (const float*)d_in[3];
    const float* fc1b = (const float*)d_in[4];
    const float* fc2w = (const float*)d_in[5];
    const float* fc2b = (const float*)d_in[6];
    float* out = (float*)d_out;

    float* pooled = (float*)d_ws;                 // B*FIN floats
    float* h      = pooled + BATCH * FIN;         // B*128 floats

    // grid: [ b(4b) | m(4b) | chunk(3b) ] = 16*16*8 = 2048 blocks
    dendrite_pool_kernel<<<2048, 256, 0, stream>>>(x, w, q, pooled);
    fc1_kernel<<<128, 256, 0, stream>>>(pooled, fc1w, fc1b, h);
    fc2_kernel<<<1, 192, 0, stream>>>(h, fc2w, fc2b, out);
}